// Round 9
// baseline (197.157 us; speedup 1.0000x reference)
//
#include <hip/hip_runtime.h>

#define HH 128
#define WW 256
#define CH 64
#define HWP (HH * WW)   // 32768

typedef __attribute__((ext_vector_type(8))) __bf16 bf16x8;
typedef __attribute__((ext_vector_type(16))) float float16;

__device__ __forceinline__ unsigned short f2bf(float f) {
    unsigned u = __float_as_uint(f);
    u += 0x7fffu + ((u >> 16) & 1u);     // RNE
    return (unsigned short)(u >> 16);
}
__device__ __forceinline__ float bf2f(unsigned short u) {
    return __uint_as_float((unsigned)u << 16);
}

// ---------------------------------------------------------------------------
// Fused weight-prep + layout transform.
// blocks [0,2048): NCHW f32 -> T-layout bf16 rows (x_left / x_right).
// blocks [2048,2416): weight fragments -> wB (layout as before).
// ---------------------------------------------------------------------------
__global__ __launch_bounds__(256) void prep_toT_k(
    const float* __restrict__ xl, const float* __restrict__ xr,
    const float* __restrict__ w1, const float* __restrict__ w2,
    const float* __restrict__ b1w, const float* __restrict__ b2w,
    const float* __restrict__ b3w, const float* __restrict__ fusw,
    unsigned short* __restrict__ XT, unsigned short* __restrict__ wB)
{
    const int tid = threadIdx.x;
    if (blockIdx.x < 2048) {
        __shared__ __align__(16) unsigned short sT[64 * 68];
        const int side = blockIdx.x >> 10;
        const int i0   = blockIdx.x & 1023;
        const int gp0  = i0 * 64;
        const int b    = gp0 >> 15;
        const int pofs = gp0 & (HWP - 1);
        const float* in = (side ? xr : xl) + (size_t)b * CH * HWP + pofs;

        for (int i = tid; i < 4096; i += 256) {
            int ci = i >> 6, px = i & 63;
            sT[px * 68 + ci] = f2bf(in[(size_t)ci * HWP + px]);
        }
        __syncthreads();
        const int px = tid >> 2, q = tid & 3;
        unsigned short* op = XT + ((size_t)(side * 2 + b) * HWP + pofs + px) * 64;
#pragma unroll
        for (int r = 0; r < 2; ++r)
            *(uint4*)&op[(q * 2 + r) * 8] = *(uint4*)&sT[px * 68 + (q * 2 + r) * 8];
        return;
    }

    int e = (blockIdx.x - 2048) * 256 + tid;      // 0..94207
    float val;
    if (e < 73728) {
        const float* w = (e < 36864) ? w1 : w2;
        int t = (e < 36864) ? e : e - 36864;
        int j = t & 7, L = (t >> 3) & 63, nb = (t >> 9) & 1, kc = t >> 10;
        int k  = kc * 16 + (L >> 5) * 8 + j;
        int n  = nb * 32 + (L & 31);
        int kd = k >> 6, ci = k & 63;
        val = w[(n * 64 + ci) * 9 + kd];
    } else {
        int t = e - 73728;
        if (t < 4096) {                       // Q: K=64, NT=2
            int j = t & 7, L = (t >> 3) & 63, i3 = t >> 9;
            int nt = i3 & 1, kc = i3 >> 1;
            int n = nt * 32 + (L & 31), k = kc * 16 + (L >> 5) * 8 + j;
            val = b1w[n * 64 + k];
        } else if (t < 12288) {               // S||R: K=64, NT=4
            t -= 4096;
            int j = t & 7, L = (t >> 3) & 63, i3 = t >> 9;
            int nt = i3 & 3, kc = i3 >> 2;
            int n = nt * 32 + (L & 31), k = kc * 16 + (L >> 5) * 8 + j;
            val = (n < 64) ? b2w[n * 64 + k] : b3w[(n - 64) * 64 + k];
        } else {                              // FUS: K=128, NT=2
            t -= 12288;
            int j = t & 7, L = (t >> 3) & 63, i3 = t >> 9;
            int nt = i3 & 1, kc = i3 >> 1;
            int n = nt * 32 + (L & 31), k = kc * 16 + (L >> 5) * 8 + j;
            val = fusw[n * 128 + k];
        }
    }
    wB[e] = f2bf(val);
}

// halo staging: 3 rows x 66 cols, 1584 coalesced 16B tasks over 256 thr
__device__ __forceinline__ void stage_halo(
    unsigned short* sA, const unsigned short* inT, int x0, int y, int tid)
{
    for (int i = tid; i < 1584; i += 256) {
        int cell = i >> 3, j = i & 7;
        int row = cell / 66, col = cell - row * 66;
        int gy = y + row - 1, gx = x0 + col - 1;
        uint4 v = make_uint4(0, 0, 0, 0);
        if ((unsigned)gy < HH && (unsigned)gx < WW)
            v = *(const uint4*)&inT[(size_t)(gy * WW + gx) * 64 + j * 8];
        *(uint4*)&sA[(row * 66 + col) * 68 + j * 8] = v;
    }
}

// ---------------------------------------------------------------------------
// conv1: T bf16 in -> lrelu -> T bf16 out.  2-OUTPUT-ROW blocks.
// grid (4,64,4): x strip 64 px, rows y0..y0+1, z = side*2+b.
// Halo 4 rows x 66 cols (35.9 KB LDS -> 4 blocks/CU, grid = 4/CU exactly).
// Each B-fragment load feeds 2 MFMAs (one per output row).
// ---------------------------------------------------------------------------
__global__ __launch_bounds__(256) void conv1_k(
    const unsigned short* __restrict__ XT, const unsigned short* __restrict__ wB,
    unsigned short* __restrict__ H1T)
{
    __shared__ __align__(16) unsigned short sA[4 * 66 * 68];   // 35904 B

    const int tid = threadIdx.x;
    const int x0  = blockIdx.x * 64;
    const int y0  = blockIdx.y * 2;
    const int sb  = blockIdx.z;
    const unsigned short* inT = XT + (size_t)sb * HWP * 64;

    for (int i = tid; i < 2112; i += 256) {
        int cell = i >> 3, j = i & 7;
        int row = cell / 66, col = cell - row * 66;
        int gy = y0 + row - 1, gx = x0 + col - 1;
        uint4 v = make_uint4(0, 0, 0, 0);
        if ((unsigned)gy < HH && (unsigned)gx < WW)
            v = *(const uint4*)&inT[(size_t)(gy * WW + gx) * 64 + j * 8];
        *(uint4*)&sA[(row * 66 + col) * 68 + j * 8] = v;
    }
    __syncthreads();

    const int lane = tid & 63, wv = tid >> 6;
    const int h = wv & 1, nw = wv >> 1;
    const int m = lane & 31, kg = lane >> 5;
    const int pxl = h * 32 + m;

    float16 acc0, acc1;
#pragma unroll
    for (int i = 0; i < 16; ++i) { acc0[i] = 0.f; acc1[i] = 0.f; }

#pragma unroll
    for (int kc = 0; kc < 36; ++kc) {
        const int kd = kc >> 2, hh = kc & 3;
        const int dy = kd / 3, dx = kd - dy * 3;
        bf16x8 bfg = *(const bf16x8*)&wB[((kc * 2 + nw) * 64 + lane) * 8];
        const int base = (dy * 66 + pxl + dx) * 68 + hh * 16 + kg * 8;
        bf16x8 af0 = *(const bf16x8*)&sA[base];
        bf16x8 af1 = *(const bf16x8*)&sA[base + 66 * 68];
        acc0 = __builtin_amdgcn_mfma_f32_32x32x16_bf16(af0, bfg, acc0, 0, 0, 0);
        acc1 = __builtin_amdgcn_mfma_f32_32x32x16_bf16(af1, bfg, acc1, 0, 0, 0);
    }

    __syncthreads();
    unsigned short* sCb = sA;                 // [128 px][ci] stride 68
    const int n = nw * 32 + (lane & 31);
#pragma unroll
    for (int r = 0; r < 16; ++r) {
        int prl = h * 32 + (r & 3) + 8 * (r >> 2) + 4 * kg;
        float v0 = acc0[r]; v0 = v0 > 0.f ? v0 : 0.1f * v0;
        float v1 = acc1[r]; v1 = v1 > 0.f ? v1 : 0.1f * v1;
        sCb[prl * 68 + n] = f2bf(v0);
        sCb[(64 + prl) * 68 + n] = f2bf(v1);
    }
    __syncthreads();

    const int px2 = tid >> 1, q = tid & 1;
    const int rr = px2 >> 6, px = px2 & 63;
    unsigned short* op = H1T + ((size_t)sb * HWP + (y0 + rr) * WW + x0 + px) * 64 + q * 32;
#pragma unroll
    for (int j = 0; j < 4; ++j)
        *(uint4*)&op[j * 8] = *(uint4*)&sCb[px2 * 68 + q * 32 + j * 8];
}

// ---------------------------------------------------------------------------
// conv2 + residual + fused 1x1 projections (round-7 structure, bf16 S/R).
// side 0 (left):  buf tile -> Q proj -> QT bf16.
// side 1 (right): buf tile -> S,R proj -> ST, RT bf16.
// ---------------------------------------------------------------------------
__global__ __launch_bounds__(256) void conv2_k(
    const unsigned short* __restrict__ H1T, const unsigned short* __restrict__ XT,
    const unsigned short* __restrict__ wB2, const unsigned short* __restrict__ wQ,
    const unsigned short* __restrict__ wSR, const float* __restrict__ b1b,
    const float* __restrict__ b2b, const float* __restrict__ b3b,
    unsigned short* __restrict__ QT, unsigned short* __restrict__ ST,
    unsigned short* __restrict__ RT)
{
    __shared__ __align__(16) unsigned short sA[3 * 66 * 68];

    const int tid = threadIdx.x;
    const int x0  = blockIdx.x * 64;
    const int y   = blockIdx.y;
    const int sb  = blockIdx.z;
    const int side = sb >> 1, b = sb & 1;
    const unsigned short* inT = H1T + (size_t)sb * HWP * 64;

    stage_halo(sA, inT, x0, y, tid);
    __syncthreads();

    const int lane = tid & 63, wv = tid >> 6;
    const int mw = wv & 1, nw = wv >> 1;
    const int m = lane & 31, kg = lane >> 5;
    const int px_l = mw * 32 + m;

    float16 acc;
#pragma unroll
    for (int i = 0; i < 16; ++i) acc[i] = 0.f;

#pragma unroll
    for (int kc = 0; kc < 36; ++kc) {
        const int kd = kc >> 2, h = kc & 3;
        const int dy = kd / 3, dx = kd - dy * 3;
        bf16x8 af = *(const bf16x8*)&sA[((dy * 66 + px_l + dx) * 68) + h * 16 + kg * 8];
        bf16x8 bf = *(const bf16x8*)&wB2[((kc * 2 + nw) * 64 + lane) * 8];
        acc = __builtin_amdgcn_mfma_f32_32x32x16_bf16(af, bf, acc, 0, 0, 0);
    }

    // residual add (bf16 x from XT) -> buf tile bf16 in sCb [px][ci]
    __syncthreads();
    unsigned short* sCb = sA;                          // halves [0, 4352)
    unsigned short* sC2 = sA + 4352;                   // proj output staging
    const int n = nw * 32 + (lane & 31);
    const unsigned short* xres = XT + (size_t)sb * HWP * 64;
#pragma unroll
    for (int r = 0; r < 16; ++r) {
        int pr = mw * 32 + (r & 3) + 8 * (r >> 2) + 4 * kg;
        float xv = bf2f(xres[(size_t)(y * WW + x0 + pr) * 64 + n]);
        sCb[pr * 68 + n] = f2bf(acc[r] + xv);
    }
    __syncthreads();

    // fused projection MFMAs (K=64)
    if (side == 0) {
        float16 a2;
#pragma unroll
        for (int i = 0; i < 16; ++i) a2[i] = 0.f;
#pragma unroll
        for (int kc = 0; kc < 4; ++kc) {
            bf16x8 af = *(const bf16x8*)&sCb[px_l * 68 + kc * 16 + kg * 8];
            bf16x8 bf = *(const bf16x8*)&wQ[((kc * 2 + nw) * 64 + lane) * 8];
            a2 = __builtin_amdgcn_mfma_f32_32x32x16_bf16(af, bf, a2, 0, 0, 0);
        }
        float bv = b1b[n];
#pragma unroll
        for (int r = 0; r < 16; ++r) {
            int pr = mw * 32 + (r & 3) + 8 * (r >> 2) + 4 * kg;
            sC2[pr * 68 + n] = f2bf(a2[r] + bv);
        }
        __syncthreads();
        const int px = tid >> 2, q = tid & 3;
        unsigned short* op = QT + ((size_t)b * HWP + y * WW + x0 + px) * 64;
#pragma unroll
        for (int r = 0; r < 2; ++r)
            *(uint4*)&op[(q * 2 + r) * 8] = *(uint4*)&sC2[px * 68 + (q * 2 + r) * 8];
    } else {
        float16 a2[2];
#pragma unroll
        for (int t = 0; t < 2; ++t)
#pragma unroll
            for (int i = 0; i < 16; ++i) a2[t][i] = 0.f;
#pragma unroll
        for (int kc = 0; kc < 4; ++kc) {
            bf16x8 af = *(const bf16x8*)&sCb[px_l * 68 + kc * 16 + kg * 8];
#pragma unroll
            for (int t = 0; t < 2; ++t) {
                int nt = nw * 2 + t;
                bf16x8 bf = *(const bf16x8*)&wSR[((kc * 4 + nt) * 64 + lane) * 8];
                a2[t] = __builtin_amdgcn_mfma_f32_32x32x16_bf16(af, bf, a2[t], 0, 0, 0);
            }
        }
#pragma unroll
        for (int t = 0; t < 2; ++t) {
            int nn = (nw * 2 + t) * 32 + (lane & 31);
            float bv = (nn < 64) ? b2b[nn] : b3b[nn - 64];
#pragma unroll
            for (int r = 0; r < 16; ++r) {
                int pr = mw * 32 + (r & 3) + 8 * (r >> 2) + 4 * kg;
                sC2[pr * 132 + nn] = f2bf(a2[t][r] + bv);
            }
        }
        __syncthreads();
        const int px = tid >> 2, q = tid & 3;
        const size_t prow = (size_t)b * HWP + y * WW + x0 + px;
        unsigned short* op = ((q < 2) ? ST : RT) + prow * 64 + (q & 1) * 32;
#pragma unroll
        for (int j = 0; j < 4; ++j)
            *(uint4*)&op[j * 8] = *(uint4*)&sC2[px * 132 + q * 32 + j * 8];
    }
}

// ---------------------------------------------------------------------------
// Merged attention + fusion conv (round-7 structure, bf16 S/R).
// Block = 64 px, 512 thr (8 waves), XCD batch swizzle via (blk&4).
// ---------------------------------------------------------------------------
__global__ __launch_bounds__(512) void attn_fuse_k(
    const unsigned short* __restrict__ QT, const unsigned short* __restrict__ ST,
    const unsigned short* __restrict__ RT, const int* __restrict__ xxs,
    const int* __restrict__ yys, const unsigned short* __restrict__ XT,
    const unsigned short* __restrict__ wfrag, const float* __restrict__ bias,
    float* __restrict__ out, float* __restrict__ Mout)
{
    __shared__ __align__(16) unsigned char smem[64 * 68 * 4];  // 17408 B
    unsigned short* sBuf = (unsigned short*)smem;            // [px][ch] str 68
    unsigned short* sXT  = (unsigned short*)smem + 64 * 68;  // [px][ch] str 68
    float*          sC   = (float*)smem;                     // [co][px] str 68

    const int tid  = threadIdx.x;
    const int lane = tid & 63;
    const int wv   = tid >> 6;

    const int blk = blockIdx.x;
    const int b   = (blk & 4) ? 1 : 0;
    const int sub = (blk >> 3) * 4 + (blk & 3);      // [0, 512)
    const int pofs = sub * 64;
    const size_t gp0   = (size_t)b * HWP + pofs;
    const size_t bbase = (size_t)b * HWP;

    // stage x_leftT rows (side 0)
    {
        const unsigned short* xlT = XT + gp0 * 64;
        int px = tid >> 3, j = tid & 7;
        *(uint4*)&sXT[px * 68 + j * 8] = *(const uint4*)&xlT[(size_t)px * 64 + j * 8];
    }

    // ---- attention: 8 px per wave ----
    const int k = lane & 15, cq = lane >> 4;
    for (int it = 0; it < 8; ++it) {
        const int pl = wv * 8 + it;
        const size_t gp = gp0 + pl;

        const int flat = xxs[gp * 16 + k] * WW + yys[gp * 16 + k];

        const unsigned short* srow = ST + (bbase + (size_t)flat) * 64 + cq * 16;
        const unsigned short* qrow = QT + gp * 64 + cq * 16;
        float s = 0.f;
#pragma unroll
        for (int hh = 0; hh < 2; ++hh) {
            uint4 sv = *(const uint4*)(srow + hh * 8);
            uint4 qv = *(const uint4*)(qrow + hh * 8);
            const unsigned* sa = (const unsigned*)&sv;
            const unsigned* qa = (const unsigned*)&qv;
#pragma unroll
            for (int d = 0; d < 4; ++d) {
                s = fmaf(__uint_as_float(sa[d] << 16),
                         __uint_as_float(qa[d] << 16), s);
                s = fmaf(__uint_as_float(sa[d] & 0xffff0000u),
                         __uint_as_float(qa[d] & 0xffff0000u), s);
            }
        }
        s += __shfl_xor(s, 16, 64);
        s += __shfl_xor(s, 32, 64);            // full score[k] on all lanes

        float mx = s;
#pragma unroll
        for (int mm = 1; mm <= 8; mm <<= 1) mx = fmaxf(mx, __shfl_xor(mx, mm, 64));
        const float e = __expf(s - mx);
        float sum = e;
#pragma unroll
        for (int mm = 1; mm <= 8; mm <<= 1) sum += __shfl_xor(sum, mm, 64);
        const float mval = e * (1.f / sum);

        if (lane < 16) Mout[gp * 16 + lane] = mval;

        const unsigned short* rbase = RT + bbase * 64;
        float acc = 0.f;
#pragma unroll
        for (int kk = 0; kk < 16; ++kk) {
            int   fi = __builtin_amdgcn_readlane(flat, kk);
            float mk = __uint_as_float(
                __builtin_amdgcn_readlane(__float_as_uint(mval), kk));
            acc = fmaf(mk, bf2f(rbase[(size_t)fi * 64 + lane]), acc);
        }
        sBuf[pl * 68 + lane] = f2bf(acc);
    }
    __syncthreads();

    // ---- fuse MFMA on waves 0-3 ----
    float16 facc;
#pragma unroll
    for (int i = 0; i < 16; ++i) facc[i] = 0.f;
    const int mw = wv & 1, nw = (wv >> 1) & 1;
    const int m = lane & 31, kg = lane >> 5;
    const int px_l = mw * 32 + m;

    if (tid < 256) {
#pragma unroll
        for (int kc = 0; kc < 8; ++kc) {
            const unsigned short* asrc = (kc < 4)
                ? &sBuf[px_l * 68 + kc * 16 + kg * 8]
                : &sXT[px_l * 68 + (kc - 4) * 16 + kg * 8];
            bf16x8 af = *(const bf16x8*)asrc;
            bf16x8 bf = *(const bf16x8*)&wfrag[((kc * 2 + nw) * 64 + lane) * 8];
            facc = __builtin_amdgcn_mfma_f32_32x32x16_bf16(af, bf, facc, 0, 0, 0);
        }
    }
    __syncthreads();   // all MFMA reads of sBuf/sXT done before sC overwrite

    if (tid < 256) {
        const int co_l = nw * 32 + (lane & 31);
#pragma unroll
        for (int r = 0; r < 16; ++r) {
            int pr = mw * 32 + (r & 3) + 8 * (r >> 2) + 4 * kg;
            sC[co_l * 68 + pr] = facc[r];
        }
    }
    __syncthreads();

    if (tid < 256) {
        const int co = tid >> 2, p0 = (tid & 3) * 16;
        const float bv = bias[co];
        float* op = out + ((size_t)b * CH + co) * HWP + pofs + p0;
#pragma unroll
        for (int q = 0; q < 4; ++q) {
            float4 v = *(float4*)&sC[co * 68 + p0 + q * 4];
            v.x += bv; v.y += bv; v.z += bv; v.w += bv;
            *(float4*)&op[q * 4] = v;
        }
    }
}

// ---------------------------------------------------------------------------
extern "C" void kernel_launch(void* const* d_in, const int* in_sizes, int n_in,
                              void* d_out, int out_size, void* d_ws, size_t ws_size,
                              hipStream_t stream)
{
    const float* x_left  = (const float*)d_in[0];
    const float* x_right = (const float*)d_in[1];
    const int*   xxs     = (const int*)d_in[2];
    const int*   yys     = (const int*)d_in[3];
    const float* rb_w1   = (const float*)d_in[5];
    const float* rb_w2   = (const float*)d_in[6];
    const float* b1_w    = (const float*)d_in[7];
    const float* b1_b    = (const float*)d_in[8];
    const float* b2_w    = (const float*)d_in[9];
    const float* b2_b    = (const float*)d_in[10];
    const float* b3_w    = (const float*)d_in[11];
    const float* b3_b    = (const float*)d_in[12];
    const float* fus_w   = (const float*)d_in[13];
    const float* fus_b   = (const float*)d_in[14];

    float* out  = (float*)d_out;                 // (2,64,128,256)
    float* Mout = out + (size_t)2 * CH * HWP;    // (2,32768,1,16)

    unsigned short* ws2 = (unsigned short*)d_ws;
    unsigned short* XT   = ws2;                  // [side][b][HWP][64]  8388608 h
    unsigned short* H1T  = ws2 + 8388608;
    unsigned short* QT   = ws2 + 16777216;       // [b][HWP][64]        4194304 h
    unsigned short* ST   = ws2 + 20971520;
    unsigned short* RT   = ws2 + 25165824;
    unsigned short* wB   = ws2 + 29360128;       // 94208 halves

    prep_toT_k<<<2416, 256, 0, stream>>>(x_left, x_right, rb_w1, rb_w2,
                                         b1_w, b2_w, b3_w, fus_w, XT, wB);

    conv1_k<<<dim3(4, 64, 4), 256, 0, stream>>>(XT, wB, H1T);
    conv2_k<<<dim3(4, 128, 4), 256, 0, stream>>>(H1T, XT, wB + 36864, wB + 73728,
                                                 wB + 77824, b1_b, b2_b, b3_b,
                                                 QT, ST, RT);

    attn_fuse_k<<<1024, 512, 0, stream>>>(QT, ST, RT, xxs, yys, XT,
                                          wB + 86016, fus_b, out, Mout);
}

// Round 10
// 192.111 us; speedup vs baseline: 1.0263x; 1.0263x over previous
//
#include <hip/hip_runtime.h>

#define HH 128
#define WW 256
#define CH 64
#define HWP (HH * WW)   // 32768

typedef __attribute__((ext_vector_type(8))) __bf16 bf16x8;
typedef __attribute__((ext_vector_type(16))) float float16;

__device__ __forceinline__ unsigned short f2bf(float f) {
    unsigned u = __float_as_uint(f);
    u += 0x7fffu + ((u >> 16) & 1u);     // RNE
    return (unsigned short)(u >> 16);
}
__device__ __forceinline__ float bf2f(unsigned short u) {
    return __uint_as_float((unsigned)u << 16);
}

// ---------------------------------------------------------------------------
// Fused weight-prep + layout transform.
// blocks [0,2048): NCHW f32 -> T-layout bf16 rows (x_left / x_right).
// blocks [2048,2416): weight fragments -> wB.
// ---------------------------------------------------------------------------
__global__ __launch_bounds__(256) void prep_toT_k(
    const float* __restrict__ xl, const float* __restrict__ xr,
    const float* __restrict__ w1, const float* __restrict__ w2,
    const float* __restrict__ b1w, const float* __restrict__ b2w,
    const float* __restrict__ b3w, const float* __restrict__ fusw,
    unsigned short* __restrict__ XT, unsigned short* __restrict__ wB)
{
    const int tid = threadIdx.x;
    if (blockIdx.x < 2048) {
        __shared__ __align__(16) unsigned short sT[64 * 68];
        const int side = blockIdx.x >> 10;
        const int i0   = blockIdx.x & 1023;
        const int gp0  = i0 * 64;
        const int b    = gp0 >> 15;
        const int pofs = gp0 & (HWP - 1);
        const float* in = (side ? xr : xl) + (size_t)b * CH * HWP + pofs;

        for (int i = tid; i < 4096; i += 256) {
            int ci = i >> 6, px = i & 63;
            sT[px * 68 + ci] = f2bf(in[(size_t)ci * HWP + px]);
        }
        __syncthreads();
        const int px = tid >> 2, q = tid & 3;
        unsigned short* op = XT + ((size_t)(side * 2 + b) * HWP + pofs + px) * 64;
#pragma unroll
        for (int r = 0; r < 2; ++r)
            *(uint4*)&op[(q * 2 + r) * 8] = *(uint4*)&sT[px * 68 + (q * 2 + r) * 8];
        return;
    }

    int e = (blockIdx.x - 2048) * 256 + tid;      // 0..94207
    float val;
    if (e < 73728) {
        const float* w = (e < 36864) ? w1 : w2;
        int t = (e < 36864) ? e : e - 36864;
        int j = t & 7, L = (t >> 3) & 63, nb = (t >> 9) & 1, kc = t >> 10;
        int k  = kc * 16 + (L >> 5) * 8 + j;
        int n  = nb * 32 + (L & 31);
        int kd = k >> 6, ci = k & 63;
        val = w[(n * 64 + ci) * 9 + kd];
    } else {
        int t = e - 73728;
        if (t < 4096) {                       // Q: K=64, NT=2
            int j = t & 7, L = (t >> 3) & 63, i3 = t >> 9;
            int nt = i3 & 1, kc = i3 >> 1;
            int n = nt * 32 + (L & 31), k = kc * 16 + (L >> 5) * 8 + j;
            val = b1w[n * 64 + k];
        } else if (t < 12288) {               // S||R: K=64, NT=4
            t -= 4096;
            int j = t & 7, L = (t >> 3) & 63, i3 = t >> 9;
            int nt = i3 & 3, kc = i3 >> 2;
            int n = nt * 32 + (L & 31), k = kc * 16 + (L >> 5) * 8 + j;
            val = (n < 64) ? b2w[n * 64 + k] : b3w[(n - 64) * 64 + k];
        } else {                              // FUS: K=128, NT=2
            t -= 12288;
            int j = t & 7, L = (t >> 3) & 63, i3 = t >> 9;
            int nt = i3 & 1, kc = i3 >> 1;
            int n = nt * 32 + (L & 31), k = kc * 16 + (L >> 5) * 8 + j;
            val = fusw[n * 128 + k];
        }
    }
    wB[e] = f2bf(val);
}

// 4-row halo staging for 512-thread blocks: 4x66 cells x 8 uint4
__device__ __forceinline__ void stage_halo4(
    unsigned short* sA, const unsigned short* inT, int x0, int y0, int tid)
{
    for (int i = tid; i < 2112; i += 512) {
        int cell = i >> 3, j = i & 7;
        int row = cell / 66, col = cell - row * 66;
        int gy = y0 + row - 1, gx = x0 + col - 1;
        uint4 v = make_uint4(0, 0, 0, 0);
        if ((unsigned)gy < HH && (unsigned)gx < WW)
            v = *(const uint4*)&inT[(size_t)(gy * WW + gx) * 64 + j * 8];
        *(uint4*)&sA[(row * 66 + col) * 68 + j * 8] = v;
    }
}

// ---------------------------------------------------------------------------
// conv1: T bf16 in -> lrelu -> T bf16 out.  512 thr / 8 waves, 2 output rows.
// grid (4,64,4).  Wave = (row, px-half, co-half) = 32px x 32co.
// 35.9 KB LDS -> 4 blocks/CU -> 32 waves/CU (max occupancy).
// ---------------------------------------------------------------------------
__global__ __launch_bounds__(512) void conv1_k(
    const unsigned short* __restrict__ XT, const unsigned short* __restrict__ wB,
    unsigned short* __restrict__ H1T)
{
    __shared__ __align__(16) unsigned short sA[4 * 66 * 68];   // 35904 B

    const int tid = threadIdx.x;
    const int x0  = blockIdx.x * 64;
    const int y0  = blockIdx.y * 2;
    const int sb  = blockIdx.z;
    const unsigned short* inT = XT + (size_t)sb * HWP * 64;

    stage_halo4(sA, inT, x0, y0, tid);
    __syncthreads();

    const int lane = tid & 63, wv = tid >> 6;       // wv in [0,8)
    const int rr = wv & 1, mw = (wv >> 1) & 1, nw = wv >> 2;
    const int m = lane & 31, kg = lane >> 5;
    const int pxl = mw * 32 + m;

    float16 acc;
#pragma unroll
    for (int i = 0; i < 16; ++i) acc[i] = 0.f;

#pragma unroll
    for (int kc = 0; kc < 36; ++kc) {
        const int kd = kc >> 2, hh = kc & 3;
        const int dy = kd / 3, dx = kd - dy * 3;
        bf16x8 af = *(const bf16x8*)&sA[((rr + dy) * 66 + pxl + dx) * 68 + hh * 16 + kg * 8];
        bf16x8 bf = *(const bf16x8*)&wB[((kc * 2 + nw) * 64 + lane) * 8];
        acc = __builtin_amdgcn_mfma_f32_32x32x16_bf16(af, bf, acc, 0, 0, 0);
    }

    __syncthreads();
    unsigned short* sCb = sA;                 // [128 px][ci] stride 68
    const int n = nw * 32 + (lane & 31);
#pragma unroll
    for (int r = 0; r < 16; ++r) {
        int pr = rr * 64 + mw * 32 + (r & 3) + 8 * (r >> 2) + 4 * kg;
        float v = acc[r];
        v = v > 0.f ? v : 0.1f * v;
        sCb[pr * 68 + n] = f2bf(v);
    }
    __syncthreads();

    const int px2 = tid >> 2, q = tid & 3;
    const int orow = px2 >> 6, px = px2 & 63;
    unsigned short* op = H1T + ((size_t)sb * HWP + (y0 + orow) * WW + x0 + px) * 64 + q * 16;
    *(uint4*)&op[0] = *(uint4*)&sCb[px2 * 68 + q * 16];
    *(uint4*)&op[8] = *(uint4*)&sCb[px2 * 68 + q * 16 + 8];
}

// ---------------------------------------------------------------------------
// conv2 + residual + fused 1x1 projections.  512 thr / 8 waves, 2 output
// rows, grid (4,64,4).  side 0: Q proj -> QT.  side 1: S then R proj
// (sequential, reusing one staging buffer) -> ST, RT.  All bf16.
// ---------------------------------------------------------------------------
__global__ __launch_bounds__(512) void conv2_k(
    const unsigned short* __restrict__ H1T, const unsigned short* __restrict__ XT,
    const unsigned short* __restrict__ wB2, const unsigned short* __restrict__ wQ,
    const unsigned short* __restrict__ wSR, const float* __restrict__ b1b,
    const float* __restrict__ b2b, const float* __restrict__ b3b,
    unsigned short* __restrict__ QT, unsigned short* __restrict__ ST,
    unsigned short* __restrict__ RT)
{
    __shared__ __align__(16) unsigned short sA[4 * 66 * 68];   // 35904 B

    const int tid = threadIdx.x;
    const int x0  = blockIdx.x * 64;
    const int y0  = blockIdx.y * 2;
    const int sb  = blockIdx.z;
    const int side = sb >> 1, b = sb & 1;
    const unsigned short* inT = H1T + (size_t)sb * HWP * 64;

    stage_halo4(sA, inT, x0, y0, tid);
    __syncthreads();

    const int lane = tid & 63, wv = tid >> 6;
    const int rr = wv & 1, mw = (wv >> 1) & 1, nw = wv >> 2;
    const int m = lane & 31, kg = lane >> 5;
    const int pxl = mw * 32 + m;

    float16 acc;
#pragma unroll
    for (int i = 0; i < 16; ++i) acc[i] = 0.f;

#pragma unroll
    for (int kc = 0; kc < 36; ++kc) {
        const int kd = kc >> 2, hh = kc & 3;
        const int dy = kd / 3, dx = kd - dy * 3;
        bf16x8 af = *(const bf16x8*)&sA[((rr + dy) * 66 + pxl + dx) * 68 + hh * 16 + kg * 8];
        bf16x8 bf = *(const bf16x8*)&wB2[((kc * 2 + nw) * 64 + lane) * 8];
        acc = __builtin_amdgcn_mfma_f32_32x32x16_bf16(af, bf, acc, 0, 0, 0);
    }

    // residual add (bf16 x from XT) -> buf tile bf16 in sCb [128 px][ci]
    __syncthreads();
    unsigned short* sCb = sA;                          // halves [0, 8704)
    unsigned short* sC2 = sA + 8704;                   // proj staging [8704,17408)
    const int n = nw * 32 + (lane & 31);
    const unsigned short* xres = XT + (size_t)sb * HWP * 64;
#pragma unroll
    for (int r = 0; r < 16; ++r) {
        int pr = rr * 64 + mw * 32 + (r & 3) + 8 * (r >> 2) + 4 * kg;
        float xv = bf2f(xres[(size_t)((y0 + (pr >> 6)) * WW + x0 + (pr & 63)) * 64 + n]);
        sCb[pr * 68 + n] = f2bf(acc[r] + xv);
    }
    __syncthreads();

    const int px2 = tid >> 2, q = tid & 3;
    const int orow = px2 >> 6, px = px2 & 63;
    const size_t prow = (size_t)b * HWP + (y0 + orow) * WW + x0 + px;

    if (side == 0) {
        float16 a2;
#pragma unroll
        for (int i = 0; i < 16; ++i) a2[i] = 0.f;
#pragma unroll
        for (int kc = 0; kc < 4; ++kc) {
            bf16x8 af = *(const bf16x8*)&sCb[(rr * 64 + pxl) * 68 + kc * 16 + kg * 8];
            bf16x8 bf = *(const bf16x8*)&wQ[((kc * 2 + nw) * 64 + lane) * 8];
            a2 = __builtin_amdgcn_mfma_f32_32x32x16_bf16(af, bf, a2, 0, 0, 0);
        }
        float bv = b1b[n];
#pragma unroll
        for (int r = 0; r < 16; ++r) {
            int pr = rr * 64 + mw * 32 + (r & 3) + 8 * (r >> 2) + 4 * kg;
            sC2[pr * 68 + n] = f2bf(a2[r] + bv);
        }
        __syncthreads();
        unsigned short* op = QT + prow * 64 + q * 16;
        *(uint4*)&op[0] = *(uint4*)&sC2[px2 * 68 + q * 16];
        *(uint4*)&op[8] = *(uint4*)&sC2[px2 * 68 + q * 16 + 8];
    } else {
        // S projection (wSR fragments nt = nw)
        float16 a2;
#pragma unroll
        for (int i = 0; i < 16; ++i) a2[i] = 0.f;
#pragma unroll
        for (int kc = 0; kc < 4; ++kc) {
            bf16x8 af = *(const bf16x8*)&sCb[(rr * 64 + pxl) * 68 + kc * 16 + kg * 8];
            bf16x8 bf = *(const bf16x8*)&wSR[((kc * 4 + nw) * 64 + lane) * 8];
            a2 = __builtin_amdgcn_mfma_f32_32x32x16_bf16(af, bf, a2, 0, 0, 0);
        }
        {
            float bv = b2b[n];
#pragma unroll
            for (int r = 0; r < 16; ++r) {
                int pr = rr * 64 + mw * 32 + (r & 3) + 8 * (r >> 2) + 4 * kg;
                sC2[pr * 68 + n] = f2bf(a2[r] + bv);
            }
        }
        __syncthreads();
        {
            unsigned short* op = ST + prow * 64 + q * 16;
            *(uint4*)&op[0] = *(uint4*)&sC2[px2 * 68 + q * 16];
            *(uint4*)&op[8] = *(uint4*)&sC2[px2 * 68 + q * 16 + 8];
        }
        __syncthreads();   // ST reads done before sC2 overwrite

        // R projection (wSR fragments nt = 2 + nw)
#pragma unroll
        for (int i = 0; i < 16; ++i) a2[i] = 0.f;
#pragma unroll
        for (int kc = 0; kc < 4; ++kc) {
            bf16x8 af = *(const bf16x8*)&sCb[(rr * 64 + pxl) * 68 + kc * 16 + kg * 8];
            bf16x8 bf = *(const bf16x8*)&wSR[((kc * 4 + 2 + nw) * 64 + lane) * 8];
            a2 = __builtin_amdgcn_mfma_f32_32x32x16_bf16(af, bf, a2, 0, 0, 0);
        }
        {
            float bv = b3b[n];
#pragma unroll
            for (int r = 0; r < 16; ++r) {
                int pr = rr * 64 + mw * 32 + (r & 3) + 8 * (r >> 2) + 4 * kg;
                sC2[pr * 68 + n] = f2bf(a2[r] + bv);
            }
        }
        __syncthreads();
        {
            unsigned short* op = RT + prow * 64 + q * 16;
            *(uint4*)&op[0] = *(uint4*)&sC2[px2 * 68 + q * 16];
            *(uint4*)&op[8] = *(uint4*)&sC2[px2 * 68 + q * 16 + 8];
        }
    }
}

// ---------------------------------------------------------------------------
// Merged attention + fusion conv (unchanged from round 9).
// Block = 64 px, 512 thr (8 waves), XCD batch swizzle via (blk&4).
// ---------------------------------------------------------------------------
__global__ __launch_bounds__(512) void attn_fuse_k(
    const unsigned short* __restrict__ QT, const unsigned short* __restrict__ ST,
    const unsigned short* __restrict__ RT, const int* __restrict__ xxs,
    const int* __restrict__ yys, const unsigned short* __restrict__ XT,
    const unsigned short* __restrict__ wfrag, const float* __restrict__ bias,
    float* __restrict__ out, float* __restrict__ Mout)
{
    __shared__ __align__(16) unsigned char smem[64 * 68 * 4];  // 17408 B
    unsigned short* sBuf = (unsigned short*)smem;            // [px][ch] str 68
    unsigned short* sXT  = (unsigned short*)smem + 64 * 68;  // [px][ch] str 68
    float*          sC   = (float*)smem;                     // [co][px] str 68

    const int tid  = threadIdx.x;
    const int lane = tid & 63;
    const int wv   = tid >> 6;

    const int blk = blockIdx.x;
    const int b   = (blk & 4) ? 1 : 0;
    const int sub = (blk >> 3) * 4 + (blk & 3);      // [0, 512)
    const int pofs = sub * 64;
    const size_t gp0   = (size_t)b * HWP + pofs;
    const size_t bbase = (size_t)b * HWP;

    // stage x_leftT rows (side 0)
    {
        const unsigned short* xlT = XT + gp0 * 64;
        int px = tid >> 3, j = tid & 7;
        *(uint4*)&sXT[px * 68 + j * 8] = *(const uint4*)&xlT[(size_t)px * 64 + j * 8];
    }

    // ---- attention: 8 px per wave ----
    const int k = lane & 15, cq = lane >> 4;
    for (int it = 0; it < 8; ++it) {
        const int pl = wv * 8 + it;
        const size_t gp = gp0 + pl;

        const int flat = xxs[gp * 16 + k] * WW + yys[gp * 16 + k];

        const unsigned short* srow = ST + (bbase + (size_t)flat) * 64 + cq * 16;
        const unsigned short* qrow = QT + gp * 64 + cq * 16;
        float s = 0.f;
#pragma unroll
        for (int hh = 0; hh < 2; ++hh) {
            uint4 sv = *(const uint4*)(srow + hh * 8);
            uint4 qv = *(const uint4*)(qrow + hh * 8);
            const unsigned* sa = (const unsigned*)&sv;
            const unsigned* qa = (const unsigned*)&qv;
#pragma unroll
            for (int d = 0; d < 4; ++d) {
                s = fmaf(__uint_as_float(sa[d] << 16),
                         __uint_as_float(qa[d] << 16), s);
                s = fmaf(__uint_as_float(sa[d] & 0xffff0000u),
                         __uint_as_float(qa[d] & 0xffff0000u), s);
            }
        }
        s += __shfl_xor(s, 16, 64);
        s += __shfl_xor(s, 32, 64);            // full score[k] on all lanes

        float mx = s;
#pragma unroll
        for (int mm = 1; mm <= 8; mm <<= 1) mx = fmaxf(mx, __shfl_xor(mx, mm, 64));
        const float e = __expf(s - mx);
        float sum = e;
#pragma unroll
        for (int mm = 1; mm <= 8; mm <<= 1) sum += __shfl_xor(sum, mm, 64);
        const float mval = e * (1.f / sum);

        if (lane < 16) Mout[gp * 16 + lane] = mval;

        const unsigned short* rbase = RT + bbase * 64;
        float acc = 0.f;
#pragma unroll
        for (int kk = 0; kk < 16; ++kk) {
            int   fi = __builtin_amdgcn_readlane(flat, kk);
            float mk = __uint_as_float(
                __builtin_amdgcn_readlane(__float_as_uint(mval), kk));
            acc = fmaf(mk, bf2f(rbase[(size_t)fi * 64 + lane]), acc);
        }
        sBuf[pl * 68 + lane] = f2bf(acc);
    }
    __syncthreads();

    // ---- fuse MFMA on waves 0-3 ----
    float16 facc;
#pragma unroll
    for (int i = 0; i < 16; ++i) facc[i] = 0.f;
    const int mw = wv & 1, nw = (wv >> 1) & 1;
    const int m = lane & 31, kg = lane >> 5;
    const int px_l = mw * 32 + m;

    if (tid < 256) {
#pragma unroll
        for (int kc = 0; kc < 8; ++kc) {
            const unsigned short* asrc = (kc < 4)
                ? &sBuf[px_l * 68 + kc * 16 + kg * 8]
                : &sXT[px_l * 68 + (kc - 4) * 16 + kg * 8];
            bf16x8 af = *(const bf16x8*)asrc;
            bf16x8 bf = *(const bf16x8*)&wfrag[((kc * 2 + nw) * 64 + lane) * 8];
            facc = __builtin_amdgcn_mfma_f32_32x32x16_bf16(af, bf, facc, 0, 0, 0);
        }
    }
    __syncthreads();   // all MFMA reads of sBuf/sXT done before sC overwrite

    if (tid < 256) {
        const int co_l = nw * 32 + (lane & 31);
#pragma unroll
        for (int r = 0; r < 16; ++r) {
            int pr = mw * 32 + (r & 3) + 8 * (r >> 2) + 4 * kg;
            sC[co_l * 68 + pr] = facc[r];
        }
    }
    __syncthreads();

    if (tid < 256) {
        const int co = tid >> 2, p0 = (tid & 3) * 16;
        const float bv = bias[co];
        float* op = out + ((size_t)b * CH + co) * HWP + pofs + p0;
#pragma unroll
        for (int q = 0; q < 4; ++q) {
            float4 v = *(float4*)&sC[co * 68 + p0 + q * 4];
            v.x += bv; v.y += bv; v.z += bv; v.w += bv;
            *(float4*)&op[q * 4] = v;
        }
    }
}

// ---------------------------------------------------------------------------
extern "C" void kernel_launch(void* const* d_in, const int* in_sizes, int n_in,
                              void* d_out, int out_size, void* d_ws, size_t ws_size,
                              hipStream_t stream)
{
    const float* x_left  = (const float*)d_in[0];
    const float* x_right = (const float*)d_in[1];
    const int*   xxs     = (const int*)d_in[2];
    const int*   yys     = (const int*)d_in[3];
    const float* rb_w1   = (const float*)d_in[5];
    const float* rb_w2   = (const float*)d_in[6];
    const float* b1_w    = (const float*)d_in[7];
    const float* b1_b    = (const float*)d_in[8];
    const float* b2_w    = (const float*)d_in[9];
    const float* b2_b    = (const float*)d_in[10];
    const float* b3_w    = (const float*)d_in[11];
    const float* b3_b    = (const float*)d_in[12];
    const float* fus_w   = (const float*)d_in[13];
    const float* fus_b   = (const float*)d_in[14];

    float* out  = (float*)d_out;                 // (2,64,128,256)
    float* Mout = out + (size_t)2 * CH * HWP;    // (2,32768,1,16)

    unsigned short* ws2 = (unsigned short*)d_ws;
    unsigned short* XT   = ws2;                  // [side][b][HWP][64]  8388608 h
    unsigned short* H1T  = ws2 + 8388608;
    unsigned short* QT   = ws2 + 16777216;       // [b][HWP][64]        4194304 h
    unsigned short* ST   = ws2 + 20971520;
    unsigned short* RT   = ws2 + 25165824;
    unsigned short* wB   = ws2 + 29360128;       // 94208 halves

    prep_toT_k<<<2416, 256, 0, stream>>>(x_left, x_right, rb_w1, rb_w2,
                                         b1_w, b2_w, b3_w, fus_w, XT, wB);

    conv1_k<<<dim3(4, 64, 4), 512, 0, stream>>>(XT, wB, H1T);
    conv2_k<<<dim3(4, 64, 4), 512, 0, stream>>>(H1T, XT, wB + 36864, wB + 73728,
                                                wB + 77824, b1_b, b2_b, b3_b,
                                                QT, ST, RT);

    attn_fuse_k<<<1024, 512, 0, stream>>>(QT, ST, RT, xxs, yys, XT,
                                          wB + 86016, fus_b, out, Mout);
}